// Round 8
// baseline (1422.631 us; speedup 1.0000x reference)
//
#include <hip/hip_runtime.h>
#include <cstddef>

#define BATCH 32
#define NPTS  1024
#define K_NN  12
#define HID   64
#define BN_EPS 1e-5f

typedef float v2f __attribute__((ext_vector_type(2)));

// ---------------------------------------------------------------------------
// d2[j] = ||x_j||^2 precompute.
// ---------------------------------------------------------------------------
template<int C>
__global__ __launch_bounds__(256) void d2_kernel(const float* __restrict__ x,
                                                 float* __restrict__ d2) {
  int gid = blockIdx.x * 256 + threadIdx.x;          // < B*N
  const float* xp = x + (size_t)gid * C;
  float s;
  if constexpr (C % 4 == 0) {
    const float4* x4 = (const float4*)xp;
    float a0 = 0.f, a1 = 0.f, a2 = 0.f, a3 = 0.f;
#pragma unroll
    for (int q = 0; q < C / 4; ++q) {
      float4 v = x4[q];
      a0 = fmaf(v.x, v.x, a0); a1 = fmaf(v.y, v.y, a1);
      a2 = fmaf(v.z, v.z, a2); a3 = fmaf(v.w, v.w, a3);
    }
    s = (a0 + a1) + (a2 + a3);
  } else {
    s = 0.f;
#pragma unroll
    for (int c = 0; c < C; ++c) { float v = xp[c]; s = fmaf(v, v, s); }
  }
  d2[gid] = s;
}

// ---------------------------------------------------------------------------
// kNN C=64 v8: NO long-lived xi array (R3-R7: allocator parks any big
// persistent array in AGPRs -> v_accvgpr_read per FMA, ~2x VALU; launch-bound
// hints never fixed it). xi block staged in LDS once; per 16-j tile keep
// acc2[16] (hot) and stream xi in two 32-ch chunks (8 ds_read_b128 each,
// transient). j wave-uniform (readfirstlane) -> xj/d2j on scalar pipe.
// 8 waves x 128-j slices (R5's proven 4 waves/SIMD TLP). Exact (d,j)
// lexicographic insert (R6's key quantization failed absmax).
// ---------------------------------------------------------------------------
__global__ __attribute__((amdgpu_flat_work_group_size(512, 512),
                          amdgpu_waves_per_eu(2, 4)))
void knn64_kernel(const float* __restrict__ x, const float* __restrict__ d2,
                  int* __restrict__ idx) {
  const int b    = blockIdx.y;
  const int lane = threadIdx.x & 63;
  const int wv_u = __builtin_amdgcn_readfirstlane(threadIdx.x >> 6);  // 0..7
  const int i0   = blockIdx.x * 64;
  const float* xb  = x  + (size_t)b * NPTS * HID;
  const float* d2b = d2 + (size_t)b * NPTS;

  constexpr int NE = 8 * K_NN;                       // 96 merge entries/row
  // xis [64][68] (17.4 KB) aliases merge arrays [64][97]x2 (49.6 KB);
  // separated by __syncthreads.
  __shared__ __align__(16) char smem[64 * (NE + 1) * 8];
  float* xis   = (float*)smem;                       // row stride 68 floats
  float* lds_d = (float*)smem;                       // [64][97]
  int*   lds_j = (int*)(smem + 64 * (NE + 1) * 4);

  {                                                  // stage xi block (coalesced)
    const float4* xg = (const float4*)(xb + (size_t)i0 * HID);
    for (int t = threadIdx.x; t < 64 * 16; t += 512) {
      int r = t >> 4, q = t & 15;
      *(float4*)&xis[r * 68 + 4 * q] = xg[r * 16 + q];
    }
  }
  __syncthreads();

  float bd[K_NN]; int bj[K_NN];
#pragma unroll
  for (int k = 0; k < K_NN; ++k) { bd[k] = 3.4e38f; bj[k] = 0x7fffffff; }

  const int j0 = wv_u * 128;                         // uniform slice base
#pragma unroll 1
  for (int jt = 0; jt < 128; jt += 16) {             // 16-j tiles
    v2f acc[16];
#pragma unroll
    for (int t = 0; t < 16; ++t) acc[t] = v2f{0.f, 0.f};

#pragma unroll
    for (int half = 0; half < 2; ++half) {           // 32-channel chunks
      const int cc = half * 32;
      v2f xi2[16];                                   // transient chunk
      const float4* xr = (const float4*)&xis[lane * 68 + cc];
#pragma unroll
      for (int q = 0; q < 8; ++q) {
        float4 v = xr[q];
        xi2[2 * q + 0] = v2f{v.x, v.y};
        xi2[2 * q + 1] = v2f{v.z, v.w};
      }
#pragma unroll
      for (int t = 0; t < 16; ++t) {
        const v2f* xj2 = (const v2f*)(xb + (size_t)(j0 + jt + t) * HID + cc);
#pragma unroll
        for (int q = 0; q < 16; ++q)                 // uniform xj -> s_load
          acc[t] = __builtin_elementwise_fma(xi2[q], xj2[q], acc[t]);
      }
    }

#pragma unroll
    for (int t = 0; t < 16; ++t) {                   // epilogue per j
      const int j = j0 + jt + t;
      const float dot = acc[t].x + acc[t].y;
      // d2_i (row-constant) dropped: doesn't change per-row top-k order.
      const float dval = fmaf(-2.f, dot, d2b[j]);
      if (dval < bd[K_NN - 1]) {                     // strict <: scanning j
        float dk = dval; int jk = j;                 // ascending keeps lower j
#pragma unroll
        for (int s = 0; s < K_NN; ++s) {             // exact branchless insert
          bool sw = dk < bd[s];
          float nd = fminf(dk, bd[s]);
          float xd = fmaxf(dk, bd[s]);
          int nj = sw ? jk : bj[s];
          int xjj = sw ? bj[s] : jk;
          bd[s] = nd; bj[s] = nj; dk = xd; jk = xjj;
        }
      }
    }
  }

  __syncthreads();                                   // xis reads done (aliasing)
#pragma unroll
  for (int k = 0; k < K_NN; ++k) {
    lds_d[lane * (NE + 1) + wv_u * K_NN + k] = bd[k];
    lds_j[lane * (NE + 1) + wv_u * K_NN + k] = bj[k];
  }
  __syncthreads();

  if (wv_u == 0) {                                   // merge 8 sorted slices
    float md[K_NN]; int mj[K_NN];
#pragma unroll
    for (int k = 0; k < K_NN; ++k) { md[k] = 3.4e38f; mj[k] = 0x7fffffff; }
    for (int e = 0; e < NE; ++e) {                   // ascending slice order
      float dk = lds_d[lane * (NE + 1) + e];
      int jk = lds_j[lane * (NE + 1) + e];
      if (dk < md[K_NN - 1]) {
#pragma unroll
        for (int s = 0; s < K_NN; ++s) {
          bool sw = dk < md[s];
          float nd = fminf(dk, md[s]);
          float xd = fmaxf(dk, md[s]);
          int nj = sw ? jk : mj[s];
          int xjj = sw ? mj[s] : jk;
          md[s] = nd; mj[s] = nj; dk = xd; jk = xjj;
        }
      }
    }
    int* op = idx + ((size_t)b * NPTS + i0 + lane) * K_NN;
#pragma unroll
    for (int k = 0; k < K_NN; ++k) op[k] = mj[k];
  }
}

// ---------------------------------------------------------------------------
// kNN C=3 (layer 0): xi[3] in registers (tiny), R5 shape: 8 waves x 128 j.
// ---------------------------------------------------------------------------
__global__ __launch_bounds__(512, 2) void knn3_kernel(
    const float* __restrict__ x, const float* __restrict__ d2,
    int* __restrict__ idx) {
  const int b    = blockIdx.y;
  const int lane = threadIdx.x & 63;
  const int wv_u = __builtin_amdgcn_readfirstlane(threadIdx.x >> 6);  // 0..7
  const int i    = blockIdx.x * 64 + lane;
  const float* xb  = x  + (size_t)b * NPTS * 3;
  const float* d2b = d2 + (size_t)b * NPTS;

  constexpr int NE = 8 * K_NN;
  __shared__ float lds_d[64][NE + 1];
  __shared__ int   lds_j[64][NE + 1];

  float xi0 = xb[(size_t)i * 3 + 0];
  float xi1 = xb[(size_t)i * 3 + 1];
  float xi2v = xb[(size_t)i * 3 + 2];

  float bd[K_NN]; int bj[K_NN];
#pragma unroll
  for (int k = 0; k < K_NN; ++k) { bd[k] = 3.4e38f; bj[k] = 0x7fffffff; }

  const int j0 = wv_u * 128;
#pragma unroll 2
  for (int jj = 0; jj < 128; ++jj) {
    const int j = j0 + jj;                           // uniform
    const float* xj = xb + (size_t)j * 3;            // uniform -> s_load
    const float d2j = d2b[j];
    float dot = fmaf(xi0, xj[0], 0.f);
    dot = fmaf(xi1, xj[1], dot);
    dot = fmaf(xi2v, xj[2], dot);
    const float dval = fmaf(-2.f, dot, d2j);
    if (dval < bd[K_NN - 1]) {
      float dk = dval; int jk = j;
#pragma unroll
      for (int s = 0; s < K_NN; ++s) {
        bool sw = dk < bd[s];
        float nd = fminf(dk, bd[s]);
        float xd = fmaxf(dk, bd[s]);
        int nj = sw ? jk : bj[s];
        int xjj = sw ? bj[s] : jk;
        bd[s] = nd; bj[s] = nj; dk = xd; jk = xjj;
      }
    }
  }

#pragma unroll
  for (int k = 0; k < K_NN; ++k) {
    lds_d[lane][wv_u * K_NN + k] = bd[k];
    lds_j[lane][wv_u * K_NN + k] = bj[k];
  }
  __syncthreads();

  if (wv_u == 0) {
    float md[K_NN]; int mj[K_NN];
#pragma unroll
    for (int k = 0; k < K_NN; ++k) { md[k] = 3.4e38f; mj[k] = 0x7fffffff; }
    for (int e = 0; e < NE; ++e) {
      float dk = lds_d[lane][e]; int jk = lds_j[lane][e];
      if (dk < md[K_NN - 1]) {
#pragma unroll
        for (int s = 0; s < K_NN; ++s) {
          bool sw = dk < md[s];
          float nd = fminf(dk, md[s]);
          float xd = fmaxf(dk, md[s]);
          int nj = sw ? jk : mj[s];
          int xjj = sw ? mj[s] : jk;
          md[s] = nd; mj[s] = nj; dk = xd; jk = xjj;
        }
      }
    }
    int* op = idx + ((size_t)b * NPTS + blockIdx.x * 64 + lane) * K_NN;
#pragma unroll
    for (int k = 0; k < K_NN; ++k) op[k] = mj[k];
  }
}

// ---------------------------------------------------------------------------
// wprep: W1c[i] = W1a[i] - W1b[i] for layers 1..3 (wa[i]: [128][64] row-major).
// ---------------------------------------------------------------------------
__global__ __launch_bounds__(256) void wprep_kernel(const float* __restrict__ wa,
                                                    float* __restrict__ w1c) {
  int t = blockIdx.x * 256 + threadIdx.x;            // < 3*4096
  int i = t >> 12, r = t & 4095;
  w1c[t] = wa[i * 8192 + r] - wa[i * 8192 + 4096 + r];
}

// ---------------------------------------------------------------------------
// rowgemm: Y[r][f] = bias[f] + scale * sum_c X[r][c] * W[c][f],  R x 64 @ 64x64.
// ---------------------------------------------------------------------------
__global__ __launch_bounds__(256) void rowgemm_kernel(
    const float* __restrict__ X, const float* __restrict__ W,
    const float* __restrict__ bias, float scale, float* __restrict__ Y) {
  __shared__ float w_s[HID * HID];
  for (int t = threadIdx.x; t < HID * HID; t += 256) w_s[t] = W[t];
  __syncthreads();

  const int lane = threadIdx.x & 63;
  const int wv   = threadIdx.x >> 6;
  const int fq   = lane & 15;                        // 4 f's: 4fq..4fq+3
  const int rg   = lane >> 4;                        // 4 row-groups x 2 rows
  const int r0   = blockIdx.x * 32 + wv * 8 + rg * 2;

  const float4* X4 = (const float4*)X;               // row = 16 float4
  const float4* W4 = (const float4*)w_s;
  float a0[4] = {0.f, 0.f, 0.f, 0.f}, a1[4] = {0.f, 0.f, 0.f, 0.f};

#pragma unroll 4
  for (int cq = 0; cq < 16; ++cq) {
    float4 xa = X4[(size_t)r0 * 16 + cq];
    float4 xb_ = X4[(size_t)(r0 + 1) * 16 + cq];
    float ea[4] = {xa.x, xa.y, xa.z, xa.w};
    float eb[4] = {xb_.x, xb_.y, xb_.z, xb_.w};
#pragma unroll
    for (int d = 0; d < 4; ++d) {
      float4 wv4 = W4[(cq * 4 + d) * 16 + fq];
      float w[4] = {wv4.x, wv4.y, wv4.z, wv4.w};
#pragma unroll
      for (int k = 0; k < 4; ++k) {
        a0[k] = fmaf(ea[d], w[k], a0[k]);
        a1[k] = fmaf(eb[d], w[k], a1[k]);
      }
    }
  }
  float bb[4] = {0.f, 0.f, 0.f, 0.f};
  if (bias) { float4 b4 = ((const float4*)bias)[fq]; bb[0]=b4.x; bb[1]=b4.y; bb[2]=b4.z; bb[3]=b4.w; }
  float4 o0, o1;
  o0.x = fmaf(scale, a0[0], bb[0]); o0.y = fmaf(scale, a0[1], bb[1]);
  o0.z = fmaf(scale, a0[2], bb[2]); o0.w = fmaf(scale, a0[3], bb[3]);
  o1.x = fmaf(scale, a1[0], bb[0]); o1.y = fmaf(scale, a1[1], bb[1]);
  o1.z = fmaf(scale, a1[2], bb[2]); o1.w = fmaf(scale, a1[3], bb[3]);
  ((float4*)Y)[(size_t)r0 * 16 + fq] = o0;
  ((float4*)Y)[(size_t)(r0 + 1) * 16 + fq] = o1;
}

// ---------------------------------------------------------------------------
// edgegather: per-edge work after the algebraic split h = hxi[n] + hxj[j].
// 1024 blocks x 32 nodes (4 waves/SIMD TLP).
// ---------------------------------------------------------------------------
template<bool STATS>
__global__ __launch_bounds__(256) void edgegather_kernel(
    const int* __restrict__ idx, const float* __restrict__ hxi,
    const float* __restrict__ hxj, const float* __restrict__ stats,
    float* __restrict__ partial, float* __restrict__ hsum) {
  const int lane = threadIdx.x & 63;
  const int wv   = __builtin_amdgcn_readfirstlane(threadIdx.x >> 6);  // uniform
  const int node0 = blockIdx.x * 32;
  float A = 0.f, Bc = 0.f;
  if constexpr (!STATS) { A = stats[128 + lane]; Bc = stats[192 + lane]; }
  float s1 = 0.f, s2 = 0.f;

#pragma unroll 1
  for (int it = 0; it < 8; ++it) {
    const int n = node0 + it * 4 + wv;               // uniform
    const int bbase = (n >> 10) << 10;               // b*N
    const int* ip = idx + (size_t)n * K_NN;          // uniform -> s_load
    int j[K_NN];
#pragma unroll
    for (int k = 0; k < K_NN; ++k) j[k] = ip[k];
    const float hv = hxi[(size_t)n * HID + lane];
    float v[K_NN];
#pragma unroll
    for (int k = 0; k < K_NN; ++k)                   // 12 independent gathers
      v[k] = hxj[(size_t)(bbase + j[k]) * HID + lane];
    if constexpr (STATS) {
#pragma unroll
      for (int k = 0; k < K_NN; ++k) { float h = hv + v[k]; s1 += h; s2 = fmaf(h, h, s2); }
    } else {
      float acc = 0.f;
#pragma unroll
      for (int k = 0; k < K_NN; ++k) { float h = hv + v[k]; acc += fmaxf(fmaf(A, h, Bc), 0.f); }
      hsum[(size_t)n * HID + lane] = acc;
    }
  }

  if constexpr (STATS) {
    __shared__ float red[4][HID];
    red[wv][lane] = s1;
    __syncthreads();
    if (threadIdx.x < HID)
      partial[(size_t)blockIdx.x * 128 + lane] =
          (red[0][lane] + red[1][lane]) + (red[2][lane] + red[3][lane]);
    __syncthreads();
    red[wv][lane] = s2;
    __syncthreads();
    if (threadIdx.x < HID)
      partial[(size_t)blockIdx.x * 128 + 64 + lane] =
          (red[0][lane] + red[1][lane]) + (red[2][lane] + red[3][lane]);
  }
}

// ---------------------------------------------------------------------------
// Reduce 1024 block-partials and finalize BN scale/shift into stats[128..255].
// ---------------------------------------------------------------------------
__global__ void bn_reduce_finalize_kernel(const float* __restrict__ g,
                                          const float* __restrict__ be,
                                          const float* __restrict__ partial,
                                          float* __restrict__ stats) {
  int t = threadIdx.x;                               // 0..127
  float a0 = 0.f, a1 = 0.f, a2 = 0.f, a3 = 0.f;
  for (int gb = 0; gb < 1024; gb += 4) {
    a0 += partial[(size_t)(gb + 0) * 128 + t];
    a1 += partial[(size_t)(gb + 1) * 128 + t];
    a2 += partial[(size_t)(gb + 2) * 128 + t];
    a3 += partial[(size_t)(gb + 3) * 128 + t];
  }
  __shared__ float sm[128];
  sm[t] = (a0 + a1) + (a2 + a3);
  __syncthreads();
  if (t < HID) {
    const float inv_n = 1.f / (float)(BATCH * NPTS * K_NN);
    float m = sm[t] * inv_n;
    float v = sm[HID + t] * inv_n - m * m;
    float A = g[t] * rsqrtf(v + BN_EPS);
    stats[128 + t] = A;
    stats[192 + t] = be[t] - m * A;
  }
}

// ---------------------------------------------------------------------------
// Old-path EdgeConv (layer 0 only, C=3).
// ---------------------------------------------------------------------------
template<int C, bool STATS>
__global__ __launch_bounds__(256) void edgeconv_kernel(
    const float* __restrict__ xcur, const int* __restrict__ idx,
    const float* __restrict__ W1, const float* __restrict__ b1,
    const float* __restrict__ W2, const float* __restrict__ b2,
    float* __restrict__ stats, float* __restrict__ out) {
  constexpr int C2 = 2 * C;
  __shared__ float w1s[C2 * HID];
  __shared__ float w2s[STATS ? 1 : HID * HID];
  __shared__ float xis[4 * C];
  __shared__ float ejs[4 * K_NN * C];
  __shared__ int   idxs[4 * K_NN];
  __shared__ float red[4 * HID];

  for (int t = threadIdx.x; t < C2 * HID; t += 256) w1s[t] = W1[t];
  if constexpr (!STATS)
    for (int t = threadIdx.x; t < HID * HID; t += 256) w2s[t] = W2[t];

  const int f  = threadIdx.x & 63;
  const int nl = threadIdx.x >> 6;
  const float b1f = b1[f];
  float A = 0.f, Bc = 0.f, b2f = 0.f;
  if constexpr (!STATS) { A = stats[2 * HID + f]; Bc = stats[3 * HID + f]; b2f = b2[f]; }
  float s1 = 0.f, s2 = 0.f;

  const int node0 = blockIdx.x * 64;
  const int nbb = (node0 >> 10) << 10;
  __syncthreads();

  for (int g4 = 0; g4 < 16; ++g4) {
    const int nbase = node0 + g4 * 4;
    __syncthreads();
    if (threadIdx.x < 4 * K_NN)
      idxs[threadIdx.x] = idx[(size_t)nbase * K_NN + threadIdx.x];
    for (int t = threadIdx.x; t < 4 * C; t += 256) {
      int n2 = t / C, c = t - n2 * C;
      xis[t] = xcur[(size_t)(nbase + n2) * C + c];
    }
    __syncthreads();
    for (int t = threadIdx.x; t < 4 * K_NN * C; t += 256) {
      int e_l = t / C, c = t - e_l * C;
      int n2 = e_l / K_NN;
      int j = idxs[e_l];
      ejs[t] = xcur[(size_t)(nbb + j) * C + c] - xis[n2 * C + c];
    }
    __syncthreads();

    float hxi = b1f;
#pragma unroll
    for (int c = 0; c < C; ++c) hxi = fmaf(xis[nl * C + c], w1s[c * HID + f], hxi);

    float hsum = 0.f;
#pragma unroll
    for (int kq = 0; kq < K_NN / 4; ++kq) {
      float h0 = hxi, h1 = hxi, h2 = hxi, h3 = hxi;
      const float* ep = ejs + (nl * K_NN + kq * 4) * C;
#pragma unroll
      for (int c = 0; c < C; ++c) {
        float w = w1s[(C + c) * HID + f];
        h0 = fmaf(ep[0 * C + c], w, h0);
        h1 = fmaf(ep[1 * C + c], w, h1);
        h2 = fmaf(ep[2 * C + c], w, h2);
        h3 = fmaf(ep[3 * C + c], w, h3);
      }
      if constexpr (STATS) {
        s1 += (h0 + h1) + (h2 + h3);
        s2 = fmaf(h0, h0, s2); s2 = fmaf(h1, h1, s2);
        s2 = fmaf(h2, h2, s2); s2 = fmaf(h3, h3, s2);
      } else {
        hsum += fmaxf(fmaf(A, h0, Bc), 0.f) + fmaxf(fmaf(A, h1, Bc), 0.f)
              + fmaxf(fmaf(A, h2, Bc), 0.f) + fmaxf(fmaf(A, h3, Bc), 0.f);
      }
    }

    if constexpr (!STATS) {
      red[nl * HID + f] = hsum;
      __syncthreads();
      float acc = 0.f;
#pragma unroll 8
      for (int h = 0; h < HID; ++h) acc = fmaf(red[nl * HID + h], w2s[h * HID + f], acc);
      out[(size_t)(nbase + nl) * HID + f] = fmaf(acc, 1.f / (float)K_NN, b2f);
    }
  }

  if constexpr (STATS) {
    red[nl * HID + f] = s1;
    __syncthreads();
    if (threadIdx.x < HID)
      atomicAdd(&stats[f], ((red[f] + red[HID + f]) + (red[2 * HID + f] + red[3 * HID + f])));
    __syncthreads();
    red[nl * HID + f] = s2;
    __syncthreads();
    if (threadIdx.x < HID)
      atomicAdd(&stats[HID + f], ((red[f] + red[HID + f]) + (red[2 * HID + f] + red[3 * HID + f])));
  }
}

__global__ void bn_finalize_kernel(const float* __restrict__ g, const float* __restrict__ be,
                                   float* __restrict__ stats) {
  int f = threadIdx.x;
  const float inv_n = 1.f / (float)(BATCH * NPTS * K_NN);
  float m = stats[f] * inv_n;
  float v = stats[HID + f] * inv_n - m * m;
  float A = g[f] * rsqrtf(v + BN_EPS);
  stats[2 * HID + f] = A;
  stats[3 * HID + f] = be[f] - m * A;
}

// ---------------------------------------------------------------------------
__global__ __launch_bounds__(256) void pool_kernel(const float* __restrict__ h,
                                                   float* __restrict__ pooled) {
  const int b = blockIdx.x;
  const int f = threadIdx.x & 63;
  const int gsz = threadIdx.x >> 6;
  __shared__ float red[4][HID];
  float s = 0.f;
  for (int n = gsz; n < NPTS; n += 4) s += h[((size_t)b * NPTS + n) * HID + f];
  red[gsz][f] = s;
  __syncthreads();
  if (threadIdx.x < HID)
    pooled[b * HID + f] = ((red[0][f] + red[1][f]) + (red[2][f] + red[3][f])) * (1.f / (float)NPTS);
}

__global__ __launch_bounds__(256) void head_kernel(const float* __restrict__ pooled,
    const float* __restrict__ wf1, const float* __restrict__ bf1,
    const float* __restrict__ gf, const float* __restrict__ bef,
    const float* __restrict__ wf2, const float* __restrict__ bf2,
    float* __restrict__ out) {
  __shared__ float pl[BATCH * HID];
  __shared__ float t[BATCH * 32];
  __shared__ float Ab[32], Bb[32];
  for (int i = threadIdx.x; i < BATCH * HID; i += 256) pl[i] = pooled[i];
  __syncthreads();
  for (int i = threadIdx.x; i < BATCH * 32; i += 256) {
    int s = i >> 5, f1 = i & 31;
    float acc = bf1[f1];
    for (int h = 0; h < HID; ++h) acc = fmaf(pl[s * HID + h], wf1[h * 32 + f1], acc);
    t[i] = acc;
  }
  __syncthreads();
  if (threadIdx.x < 32) {
    int f1 = threadIdx.x;
    float m = 0.f;
    for (int s = 0; s < BATCH; ++s) m += t[s * 32 + f1];
    m *= (1.f / (float)BATCH);
    float v = 0.f;
    for (int s = 0; s < BATCH; ++s) { float d = t[s * 32 + f1] - m; v = fmaf(d, d, v); }
    v *= (1.f / (float)BATCH);
    float A = gf[f1] * rsqrtf(v + BN_EPS);
    Ab[f1] = A; Bb[f1] = bef[f1] - m * A;
  }
  __syncthreads();
  for (int i = threadIdx.x; i < BATCH * 32; i += 256) {
    int f1 = i & 31;
    t[i] = fmaxf(fmaf(Ab[f1], t[i], Bb[f1]), 0.f);
  }
  __syncthreads();
  if (threadIdx.x < BATCH * 2) {
    int s = threadIdx.x >> 1, o = threadIdx.x & 1;
    float acc = bf2[o];
    for (int f1 = 0; f1 < 32; ++f1) acc = fmaf(t[s * 32 + f1], wf2[f1 * 2 + o], acc);
    out[s * 2 + o] = acc;
  }
}

// ---------------------------------------------------------------------------
extern "C" void kernel_launch(void* const* d_in, const int* in_sizes, int n_in,
                              void* d_out, int out_size, void* d_ws, size_t ws_size,
                              hipStream_t stream) {
  const float* x   = (const float*)d_in[0];
  const float* w0a = (const float*)d_in[1];
  const float* b0a = (const float*)d_in[2];
  const float* g0  = (const float*)d_in[3];
  const float* be0 = (const float*)d_in[4];
  const float* w0b = (const float*)d_in[5];
  const float* b0b = (const float*)d_in[6];
  const float* wa  = (const float*)d_in[7];
  const float* ba  = (const float*)d_in[8];
  const float* ga  = (const float*)d_in[9];
  const float* bea = (const float*)d_in[10];
  const float* wb  = (const float*)d_in[11];
  const float* bb  = (const float*)d_in[12];
  const float* wf1 = (const float*)d_in[13];
  const float* bf1 = (const float*)d_in[14];
  const float* gf  = (const float*)d_in[15];
  const float* bef = (const float*)d_in[16];
  const float* wf2 = (const float*)d_in[17];
  const float* bf2 = (const float*)d_in[18];

  float* ws = (float*)d_ws;
  const size_t HN = (size_t)BATCH * NPTS * HID;         // 2,097,152
  const size_t ROWS = (size_t)BATCH * NPTS;             // 32768
  float* bufA    = ws;                                  // HN
  float* bufB    = bufA + HN;                           // HN
  float* hxi     = bufB + HN;                           // HN
  float* hxjb    = hxi + HN;                            // HN
  float* hsm     = hxjb + HN;                           // HN
  float* w1c     = hsm + HN;                            // 3*4096
  int*   idxb    = (int*)(w1c + 3 * 4096);              // ROWS*12
  float* d2buf   = (float*)(idxb + ROWS * K_NN);        // ROWS
  float* stats   = d2buf + ROWS;                        // 256
  float* partial = stats + 256;                         // 1024*128
  float* pooled  = partial + 1024 * 128;                // 2048
  // total ~45 MB of workspace

  wprep_kernel<<<48, 256, 0, stream>>>(wa, w1c);

  // ---- layer 0 (C=3, old path) ----
  d2_kernel<3><<<(int)(ROWS / 256), 256, 0, stream>>>(x, d2buf);
  knn3_kernel<<<dim3(16, BATCH), 512, 0, stream>>>(x, d2buf, idxb);
  hipMemsetAsync(stats, 0, 2 * HID * sizeof(float), stream);
  edgeconv_kernel<3, true ><<<512, 256, 0, stream>>>(x, idxb, w0a, b0a, nullptr, nullptr, stats, nullptr);
  bn_finalize_kernel<<<1, HID, 0, stream>>>(g0, be0, stats);
  edgeconv_kernel<3, false><<<512, 256, 0, stream>>>(x, idxb, w0a, b0a, w0b, b0b, stats, bufA);

  // ---- layers 1..3 (gather path) ----
  const float* cur = bufA;
  float* nxt = bufB;
  for (int i = 0; i < 3; ++i) {
    const float* W1b = wa + (size_t)i * 8192 + 4096;
    d2_kernel<HID><<<(int)(ROWS / 256), 256, 0, stream>>>(cur, d2buf);
    knn64_kernel<<<dim3(16, BATCH), 512, 0, stream>>>(cur, d2buf, idxb);
    rowgemm_kernel<<<(int)(ROWS / 32), 256, 0, stream>>>(cur, w1c + (size_t)i * 4096,
                                                         ba + i * HID, 1.0f, hxi);
    rowgemm_kernel<<<(int)(ROWS / 32), 256, 0, stream>>>(cur, W1b, nullptr, 1.0f, hxjb);
    edgegather_kernel<true ><<<1024, 256, 0, stream>>>(idxb, hxi, hxjb, nullptr, partial, nullptr);
    bn_reduce_finalize_kernel<<<1, 128, 0, stream>>>(ga + i * HID, bea + i * HID, partial, stats);
    edgegather_kernel<false><<<1024, 256, 0, stream>>>(idxb, hxi, hxjb, stats, nullptr, hsm);
    rowgemm_kernel<<<(int)(ROWS / 32), 256, 0, stream>>>(hsm, wb + (size_t)i * 4096,
                                                         bb + i * HID, 1.f / (float)K_NN, nxt);
    const float* t = cur; cur = nxt; nxt = (float*)t;
  }

  pool_kernel<<<BATCH, 256, 0, stream>>>(cur, pooled);
  head_kernel<<<1, 256, 0, stream>>>(pooled, wf1, bf1, gf, bef, wf2, bf2, (float*)d_out);
}

// Round 9
// 1079.846 us; speedup vs baseline: 1.3174x; 1.3174x over previous
//
#include <hip/hip_runtime.h>
#include <cstddef>

#define BATCH 32
#define NPTS  1024
#define K_NN  12
#define HID   64
#define BN_EPS 1e-5f

typedef float v2f __attribute__((ext_vector_type(2)));

// ---------------------------------------------------------------------------
// d2[j] = ||x_j||^2 precompute.
// ---------------------------------------------------------------------------
template<int C>
__global__ __launch_bounds__(256) void d2_kernel(const float* __restrict__ x,
                                                 float* __restrict__ d2) {
  int gid = blockIdx.x * 256 + threadIdx.x;          // < B*N
  const float* xp = x + (size_t)gid * C;
  float s;
  if constexpr (C % 4 == 0) {
    const float4* x4 = (const float4*)xp;
    float a0 = 0.f, a1 = 0.f, a2 = 0.f, a3 = 0.f;
#pragma unroll
    for (int q = 0; q < C / 4; ++q) {
      float4 v = x4[q];
      a0 = fmaf(v.x, v.x, a0); a1 = fmaf(v.y, v.y, a1);
      a2 = fmaf(v.z, v.z, a2); a3 = fmaf(v.w, v.w, a3);
    }
    s = (a0 + a1) + (a2 + a3);
  } else {
    s = 0.f;
#pragma unroll
    for (int c = 0; c < C; ++c) { float v = xp[c]; s = fmaf(v, v, s); }
  }
  d2[gid] = s;
}

// ---------------------------------------------------------------------------
// kNN v9 = R5's proven structure (218 us) + pk_fma dot + unroll 2.
// lane = point i; xi persistent (allocator parks it in AGPRs - accepted, the
// 5 attempts to stop that all failed or regressed). j wave-uniform via
// readfirstlane -> xj/d2j on scalar pipe. 8 waves x 128-j slices, LDS merge.
// EXACT (d,j) lexicographic insert (R6 quantization failed absmax).
// ---------------------------------------------------------------------------
template<int C>
__global__ __launch_bounds__(512, 2) void knn_kernel(
    const float* __restrict__ x, const float* __restrict__ d2,
    int* __restrict__ idx) {
  const int b    = blockIdx.y;
  const int lane = threadIdx.x & 63;
  const int wv_u = __builtin_amdgcn_readfirstlane(threadIdx.x >> 6);  // 0..7
  const int i    = blockIdx.x * 64 + lane;
  const float* xb  = x  + (size_t)b * NPTS * C;
  const float* d2b = d2 + (size_t)b * NPTS;

  constexpr int NE = 8 * K_NN;                       // 96 merge entries/row
  __shared__ float lds_d[64][NE + 1];                // stride 97: no conflicts
  __shared__ int   lds_j[64][NE + 1];

  constexpr int CP = (C % 4 == 0) ? C / 2 : 1;
  v2f   xi2[CP];                                     // C%4==0 path
  float xis[(C % 4 == 0) ? 1 : C];                   // small-C path
  if constexpr (C % 4 == 0) {
    const float4* xr = (const float4*)(xb + (size_t)i * C);
#pragma unroll
    for (int q = 0; q < C / 4; ++q) {
      float4 v = xr[q];
      xi2[2 * q + 0] = v2f{v.x, v.y};
      xi2[2 * q + 1] = v2f{v.z, v.w};
    }
#pragma unroll
    for (int q = 0; q < CP; ++q) asm volatile("" : "+v"(xi2[q]));  // no remat
  } else {
#pragma unroll
    for (int c = 0; c < C; ++c) xis[c] = xb[(size_t)i * C + c];
  }

  float bd[K_NN]; int bj[K_NN];
#pragma unroll
  for (int k = 0; k < K_NN; ++k) { bd[k] = 3.4e38f; bj[k] = 0x7fffffff; }

  const int j0 = wv_u * 128;                         // uniform slice base
#pragma unroll 2
  for (int jj = 0; jj < 128; ++jj) {
    const int j = j0 + jj;                           // uniform
    const float* xj = xb + (size_t)j * C;            // uniform -> s_load
    const float d2j = d2b[j];                        // uniform -> s_load
    float dot;
    if constexpr (C % 4 == 0) {
      const v2f* xj2 = (const v2f*)xj;
      v2f a0{0.f, 0.f}, a1{0.f, 0.f}, a2{0.f, 0.f}, a3{0.f, 0.f};
#pragma unroll
      for (int q = 0; q < CP; q += 4) {
        a0 = __builtin_elementwise_fma(xi2[q + 0], xj2[q + 0], a0);
        a1 = __builtin_elementwise_fma(xi2[q + 1], xj2[q + 1], a1);
        a2 = __builtin_elementwise_fma(xi2[q + 2], xj2[q + 2], a2);
        a3 = __builtin_elementwise_fma(xi2[q + 3], xj2[q + 3], a3);
      }
      v2f as = (a0 + a1) + (a2 + a3);
      dot = as.x + as.y;
    } else {
      dot = 0.f;
#pragma unroll
      for (int c = 0; c < C; ++c) dot = fmaf(xis[c], xj[c], dot);
    }
    // d2_i (row-constant) dropped: doesn't change per-row top-k order.
    const float dval = fmaf(-2.f, dot, d2j);
    if (dval < bd[K_NN - 1]) {                       // strict <: scanning j
      float dk = dval; int jk = j;                   // ascending keeps lower j
#pragma unroll
      for (int s = 0; s < K_NN; ++s) {               // exact branchless insert
        bool sw = dk < bd[s];
        float nd = fminf(dk, bd[s]);
        float xd = fmaxf(dk, bd[s]);
        int nj = sw ? jk : bj[s];
        int xjj = sw ? bj[s] : jk;
        bd[s] = nd; bj[s] = nj; dk = xd; jk = xjj;
      }
    }
  }

#pragma unroll
  for (int k = 0; k < K_NN; ++k) {
    lds_d[lane][wv_u * K_NN + k] = bd[k];
    lds_j[lane][wv_u * K_NN + k] = bj[k];
  }
  __syncthreads();

  if (wv_u == 0) {                                   // merge 8 sorted slices
    float md[K_NN]; int mj[K_NN];
#pragma unroll
    for (int k = 0; k < K_NN; ++k) { md[k] = 3.4e38f; mj[k] = 0x7fffffff; }
    for (int e = 0; e < NE; ++e) {                   // ascending slice order
      float dk = lds_d[lane][e]; int jk = lds_j[lane][e];
      if (dk < md[K_NN - 1]) {
#pragma unroll
        for (int s = 0; s < K_NN; ++s) {
          bool sw = dk < md[s];
          float nd = fminf(dk, md[s]);
          float xd = fmaxf(dk, md[s]);
          int nj = sw ? jk : mj[s];
          int xjj = sw ? mj[s] : jk;
          md[s] = nd; mj[s] = nj; dk = xd; jk = xjj;
        }
      }
    }
    int* op = idx + ((size_t)b * NPTS + blockIdx.x * 64 + lane) * K_NN;
#pragma unroll
    for (int k = 0; k < K_NN; ++k) op[k] = mj[k];
  }
}

// ---------------------------------------------------------------------------
// wprep: W1c = W1a - W1b for all 4 layers.
// layers 1..3: wa[i]: [128][64] -> w1c[i*4096 + r], r<4096.
// layer 0: w0a: [6][64], A=rows 0..2, B=rows 3..5 -> w1c[12288 + r], r<192.
// ---------------------------------------------------------------------------
__global__ __launch_bounds__(256) void wprep_kernel(const float* __restrict__ wa,
                                                    const float* __restrict__ w0a,
                                                    float* __restrict__ w1c) {
  int t = blockIdx.x * 256 + threadIdx.x;
  if (t < 12288) {
    int i = t >> 12, r = t & 4095;
    w1c[t] = wa[i * 8192 + r] - wa[i * 8192 + 4096 + r];
  } else if (t < 12288 + 192) {
    int r = t - 12288;
    w1c[t] = w0a[r] - w0a[192 + r];
  }
}

// ---------------------------------------------------------------------------
// rowgemm2: dual-output 64x64 rowgemm. YA[r][f] = biasA[f] + X[r]@WA[.][f],
// YB[r][f] = X[r]@WB[.][f]. X read once (vs two separate kernels).
// ---------------------------------------------------------------------------
__global__ __launch_bounds__(256) void rowgemm2_kernel(
    const float* __restrict__ X, const float* __restrict__ WA,
    const float* __restrict__ biasA, const float* __restrict__ WB,
    float* __restrict__ YA, float* __restrict__ YB) {
  __shared__ float wsa[HID * HID];
  __shared__ float wsb[HID * HID];
  for (int t = threadIdx.x; t < HID * HID; t += 256) { wsa[t] = WA[t]; wsb[t] = WB[t]; }
  __syncthreads();

  const int lane = threadIdx.x & 63;
  const int wv   = threadIdx.x >> 6;
  const int fq   = lane & 15;                        // 4 f's
  const int rg   = lane >> 4;                        // 4 row-groups x 2 rows
  const int r0   = blockIdx.x * 32 + wv * 8 + rg * 2;

  const float4* X4 = (const float4*)X;
  const float4* WA4 = (const float4*)wsa;
  const float4* WB4 = (const float4*)wsb;
  float aA0[4] = {0,0,0,0}, aA1[4] = {0,0,0,0};
  float aB0[4] = {0,0,0,0}, aB1[4] = {0,0,0,0};

#pragma unroll 2
  for (int cq = 0; cq < 16; ++cq) {
    float4 xa = X4[(size_t)r0 * 16 + cq];
    float4 xb_ = X4[(size_t)(r0 + 1) * 16 + cq];
    float ea[4] = {xa.x, xa.y, xa.z, xa.w};
    float eb[4] = {xb_.x, xb_.y, xb_.z, xb_.w};
#pragma unroll
    for (int d = 0; d < 4; ++d) {
      float4 wa4 = WA4[(cq * 4 + d) * 16 + fq];
      float4 wb4 = WB4[(cq * 4 + d) * 16 + fq];
      float wA[4] = {wa4.x, wa4.y, wa4.z, wa4.w};
      float wB[4] = {wb4.x, wb4.y, wb4.z, wb4.w};
#pragma unroll
      for (int k = 0; k < 4; ++k) {
        aA0[k] = fmaf(ea[d], wA[k], aA0[k]);
        aA1[k] = fmaf(eb[d], wA[k], aA1[k]);
        aB0[k] = fmaf(ea[d], wB[k], aB0[k]);
        aB1[k] = fmaf(eb[d], wB[k], aB1[k]);
      }
    }
  }
  float4 b4 = ((const float4*)biasA)[fq];
  float4 oA0{aA0[0] + b4.x, aA0[1] + b4.y, aA0[2] + b4.z, aA0[3] + b4.w};
  float4 oA1{aA1[0] + b4.x, aA1[1] + b4.y, aA1[2] + b4.z, aA1[3] + b4.w};
  float4 oB0{aB0[0], aB0[1], aB0[2], aB0[3]};
  float4 oB1{aB1[0], aB1[1], aB1[2], aB1[3]};
  ((float4*)YA)[(size_t)r0 * 16 + fq] = oA0;
  ((float4*)YA)[(size_t)(r0 + 1) * 16 + fq] = oA1;
  ((float4*)YB)[(size_t)r0 * 16 + fq] = oB0;
  ((float4*)YB)[(size_t)(r0 + 1) * 16 + fq] = oB1;
}

// ---------------------------------------------------------------------------
// dual3: layer-0 projections (C=3). hxi[n][f] = x[n]@(A-B)[.][f] + b1[f],
// hxj[n][f] = x[n]@B[.][f].  A-B = w1c0 (192 floats), B = w0a rows 3..5.
// n wave-uniform -> x row via s_load; lane = f.
// ---------------------------------------------------------------------------
__global__ __launch_bounds__(256) void dual3_kernel(
    const float* __restrict__ x, const float* __restrict__ w1c0,
    const float* __restrict__ w0a, const float* __restrict__ b1,
    float* __restrict__ hxi, float* __restrict__ hxj) {
  __shared__ float Cs[3 * HID], Bs[3 * HID], bs[HID];
  for (int t = threadIdx.x; t < 3 * HID; t += 256) {
    Cs[t] = w1c0[t];
    Bs[t] = w0a[192 + t];
  }
  if (threadIdx.x < HID) bs[threadIdx.x] = b1[threadIdx.x];
  __syncthreads();

  const int lane = threadIdx.x & 63;
  const int wv   = __builtin_amdgcn_readfirstlane(threadIdx.x >> 6);
  const int node0 = blockIdx.x * 32;
#pragma unroll 1
  for (int it = 0; it < 8; ++it) {
    const int n = node0 + it * 4 + wv;               // uniform
    const float* xr = x + (size_t)n * 3;             // uniform -> s_load
    float x0 = xr[0], x1 = xr[1], x2 = xr[2];
    float hi = bs[lane];
    hi = fmaf(x0, Cs[0 * HID + lane], hi);
    hi = fmaf(x1, Cs[1 * HID + lane], hi);
    hi = fmaf(x2, Cs[2 * HID + lane], hi);
    float hj = x0 * Bs[0 * HID + lane];
    hj = fmaf(x1, Bs[1 * HID + lane], hj);
    hj = fmaf(x2, Bs[2 * HID + lane], hj);
    hxi[(size_t)n * HID + lane] = hi;
    hxj[(size_t)n * HID + lane] = hj;
  }
}

// ---------------------------------------------------------------------------
// egstats: BN sum/sumsq over all edges of h = hxi[n] + hxj[j].
// Deterministic block partials [1024][128].
// ---------------------------------------------------------------------------
__global__ __launch_bounds__(256) void egstats_kernel(
    const int* __restrict__ idx, const float* __restrict__ hxi,
    const float* __restrict__ hxj, float* __restrict__ partial) {
  const int lane = threadIdx.x & 63;
  const int wv   = __builtin_amdgcn_readfirstlane(threadIdx.x >> 6);
  const int node0 = blockIdx.x * 32;
  float s1 = 0.f, s2 = 0.f;

#pragma unroll 1
  for (int it = 0; it < 8; ++it) {
    const int n = node0 + it * 4 + wv;               // uniform
    const int bbase = (n >> 10) << 10;               // b*N
    const int* ip = idx + (size_t)n * K_NN;          // uniform -> s_load
    int j[K_NN];
#pragma unroll
    for (int k = 0; k < K_NN; ++k) j[k] = ip[k];
    const float hv = hxi[(size_t)n * HID + lane];
    float v[K_NN];
#pragma unroll
    for (int k = 0; k < K_NN; ++k)                   // 12 independent gathers
      v[k] = hxj[(size_t)(bbase + j[k]) * HID + lane];
#pragma unroll
    for (int k = 0; k < K_NN; ++k) { float h = hv + v[k]; s1 += h; s2 = fmaf(h, h, s2); }
  }

  __shared__ float red[4][HID];
  red[wv][lane] = s1;
  __syncthreads();
  if (threadIdx.x < HID)
    partial[(size_t)blockIdx.x * 128 + lane] =
        (red[0][lane] + red[1][lane]) + (red[2][lane] + red[3][lane]);
  __syncthreads();
  red[wv][lane] = s2;
  __syncthreads();
  if (threadIdx.x < HID)
    partial[(size_t)blockIdx.x * 128 + 64 + lane] =
        (red[0][lane] + red[1][lane]) + (red[2][lane] + red[3][lane]);
}

// ---------------------------------------------------------------------------
// Reduce 1024 block-partials, finalize BN scale/shift into stats[128..255].
// ---------------------------------------------------------------------------
__global__ void bn_reduce_finalize_kernel(const float* __restrict__ g,
                                          const float* __restrict__ be,
                                          const float* __restrict__ partial,
                                          float* __restrict__ stats) {
  int t = threadIdx.x;                               // 0..127
  float a0 = 0.f, a1 = 0.f, a2 = 0.f, a3 = 0.f;
  for (int gb = 0; gb < 1024; gb += 4) {
    a0 += partial[(size_t)(gb + 0) * 128 + t];
    a1 += partial[(size_t)(gb + 1) * 128 + t];
    a2 += partial[(size_t)(gb + 2) * 128 + t];
    a3 += partial[(size_t)(gb + 3) * 128 + t];
  }
  __shared__ float sm[128];
  sm[t] = (a0 + a1) + (a2 + a3);
  __syncthreads();
  if (t < HID) {
    const float inv_n = 1.f / (float)(BATCH * NPTS * K_NN);
    float m = sm[t] * inv_n;
    float v = sm[HID + t] * inv_n - m * m;
    float A = g[t] * rsqrtf(v + BN_EPS);
    stats[128 + t] = A;
    stats[192 + t] = be[t] - m * A;
  }
}

// ---------------------------------------------------------------------------
// egapply_gemm: fused BN-apply + relu + mean-over-K + W2 + b2.
// Phase 1: hsum[n][f] = sum_k relu(A*(hxi[n]+hxj[j_k])+B) -> LDS red[32][64].
// Phase 2: out[n][f'] = b2[f'] + (1/12) * sum_f red[n][f] * W2[f][f'].
// ---------------------------------------------------------------------------
__global__ __launch_bounds__(256) void egapply_gemm_kernel(
    const int* __restrict__ idx, const float* __restrict__ hxi,
    const float* __restrict__ hxj, const float* __restrict__ stats,
    const float* __restrict__ W2, const float* __restrict__ b2,
    float* __restrict__ out) {
  __shared__ float w2s[HID * HID];
  __shared__ float red[32][HID];
  for (int t = threadIdx.x; t < HID * HID; t += 256) w2s[t] = W2[t];

  const int lane = threadIdx.x & 63;
  const int wv   = __builtin_amdgcn_readfirstlane(threadIdx.x >> 6);
  const int node0 = blockIdx.x * 32;
  const float A = stats[128 + lane], Bc = stats[192 + lane];

#pragma unroll 1
  for (int it = 0; it < 8; ++it) {
    const int n = node0 + it * 4 + wv;               // uniform
    const int bbase = (n >> 10) << 10;
    const int* ip = idx + (size_t)n * K_NN;          // uniform -> s_load
    int j[K_NN];
#pragma unroll
    for (int k = 0; k < K_NN; ++k) j[k] = ip[k];
    const float hv = hxi[(size_t)n * HID + lane];
    float v[K_NN];
#pragma unroll
    for (int k = 0; k < K_NN; ++k)
      v[k] = hxj[(size_t)(bbase + j[k]) * HID + lane];
    float acc = 0.f;
#pragma unroll
    for (int k = 0; k < K_NN; ++k) { float h = hv + v[k]; acc += fmaxf(fmaf(A, h, Bc), 0.f); }
    red[it * 4 + wv][lane] = acc;
  }
  __syncthreads();

  const float b2f = b2[lane];
  const float inv = 1.f / (float)K_NN;
#pragma unroll 2
  for (int p = 0; p < 8; ++p) {
    int r = p * 4 + wv;                              // uniform row
    float acc = 0.f;
#pragma unroll 8
    for (int h = 0; h < HID; ++h) acc = fmaf(red[r][h], w2s[h * HID + lane], acc);
    out[(size_t)(node0 + r) * HID + lane] = fmaf(acc, inv, b2f);
  }
}

// ---------------------------------------------------------------------------
__global__ __launch_bounds__(256) void pool_kernel(const float* __restrict__ h,
                                                   float* __restrict__ pooled) {
  const int b = blockIdx.x;
  const int f = threadIdx.x & 63;
  const int gsz = threadIdx.x >> 6;
  __shared__ float red[4][HID];
  float s = 0.f;
  for (int n = gsz; n < NPTS; n += 4) s += h[((size_t)b * NPTS + n) * HID + f];
  red[gsz][f] = s;
  __syncthreads();
  if (threadIdx.x < HID)
    pooled[b * HID + f] = ((red[0][f] + red[1][f]) + (red[2][f] + red[3][f])) * (1.f / (float)NPTS);
}

__global__ __launch_bounds__(256) void head_kernel(const float* __restrict__ pooled,
    const float* __restrict__ wf1, const float* __restrict__ bf1,
    const float* __restrict__ gf, const float* __restrict__ bef,
    const float* __restrict__ wf2, const float* __restrict__ bf2,
    float* __restrict__ out) {
  __shared__ float pl[BATCH * HID];
  __shared__ float t[BATCH * 32];
  __shared__ float Ab[32], Bb[32];
  for (int i = threadIdx.x; i < BATCH * HID; i += 256) pl[i] = pooled[i];
  __syncthreads();
  for (int i = threadIdx.x; i < BATCH * 32; i += 256) {
    int s = i >> 5, f1 = i & 31;
    float acc = bf1[f1];
    for (int h = 0; h < HID; ++h) acc = fmaf(pl[s * HID + h], wf1[h * 32 + f1], acc);
    t[i] = acc;
  }
  __syncthreads();
  if (threadIdx.x < 32) {
    int f1 = threadIdx.x;
    float m = 0.f;
    for (int s = 0; s < BATCH; ++s) m += t[s * 32 + f1];
    m *= (1.f / (float)BATCH);
    float v = 0.f;
    for (int s = 0; s < BATCH; ++s) { float d = t[s * 32 + f1] - m; v = fmaf(d, d, v); }
    v *= (1.f / (float)BATCH);
    float A = gf[f1] * rsqrtf(v + BN_EPS);
    Ab[f1] = A; Bb[f1] = bef[f1] - m * A;
  }
  __syncthreads();
  for (int i = threadIdx.x; i < BATCH * 32; i += 256) {
    int f1 = i & 31;
    t[i] = fmaxf(fmaf(Ab[f1], t[i], Bb[f1]), 0.f);
  }
  __syncthreads();
  if (threadIdx.x < BATCH * 2) {
    int s = threadIdx.x >> 1, o = threadIdx.x & 1;
    float acc = bf2[o];
    for (int f1 = 0; f1 < 32; ++f1) acc = fmaf(t[s * 32 + f1], wf2[f1 * 2 + o], acc);
    out[s * 2 + o] = acc;
  }
}

// ---------------------------------------------------------------------------
extern "C" void kernel_launch(void* const* d_in, const int* in_sizes, int n_in,
                              void* d_out, int out_size, void* d_ws, size_t ws_size,
                              hipStream_t stream) {
  const float* x   = (const float*)d_in[0];
  const float* w0a = (const float*)d_in[1];
  const float* b0a = (const float*)d_in[2];
  const float* g0  = (const float*)d_in[3];
  const float* be0 = (const float*)d_in[4];
  const float* w0b = (const float*)d_in[5];
  const float* b0b = (const float*)d_in[6];
  const float* wa  = (const float*)d_in[7];
  const float* ba  = (const float*)d_in[8];
  const float* ga  = (const float*)d_in[9];
  const float* bea = (const float*)d_in[10];
  const float* wb  = (const float*)d_in[11];
  const float* bb  = (const float*)d_in[12];
  const float* wf1 = (const float*)d_in[13];
  const float* bf1 = (const float*)d_in[14];
  const float* gf  = (const float*)d_in[15];
  const float* bef = (const float*)d_in[16];
  const float* wf2 = (const float*)d_in[17];
  const float* bf2 = (const float*)d_in[18];

  float* ws = (float*)d_ws;
  const size_t HN = (size_t)BATCH * NPTS * HID;         // 2,097,152
  const size_t ROWS = (size_t)BATCH * NPTS;             // 32768
  float* bufA    = ws;                                  // HN
  float* bufB    = bufA + HN;                           // HN
  float* hxi     = bufB + HN;                           // HN
  float* hxjb    = hxi + HN;                            // HN
  float* w1c     = hxjb + HN;                           // 12288+192 (pad 12544)
  int*   idxb    = (int*)(w1c + 12544);                 // ROWS*12
  float* d2buf   = (float*)(idxb + ROWS * K_NN);        // ROWS
  float* stats   = d2buf + ROWS;                        // 256
  float* partial = stats + 256;                         // 1024*128
  float* pooled  = partial + 1024 * 128;                // 2048
  // total ~34 MB of workspace

  wprep_kernel<<<49, 256, 0, stream>>>(wa, w0a, w1c);

  // ---- layer 0 (C=3, gather path) ----
  d2_kernel<3><<<(int)(ROWS / 256), 256, 0, stream>>>(x, d2buf);
  knn_kernel<3><<<dim3(16, BATCH), 512, 0, stream>>>(x, d2buf, idxb);
  dual3_kernel<<<1024, 256, 0, stream>>>(x, w1c + 12288, w0a, b0a, hxi, hxjb);
  egstats_kernel<<<1024, 256, 0, stream>>>(idxb, hxi, hxjb, partial);
  bn_reduce_finalize_kernel<<<1, 128, 0, stream>>>(g0, be0, partial, stats);
  egapply_gemm_kernel<<<1024, 256, 0, stream>>>(idxb, hxi, hxjb, stats, w0b, b0b, bufA);

  // ---- layers 1..3 (gather path) ----
  const float* cur = bufA;
  float* nxt = bufB;
  for (int i = 0; i < 3; ++i) {
    const float* W1b = wa + (size_t)i * 8192 + 4096;
    d2_kernel<HID><<<(int)(ROWS / 256), 256, 0, stream>>>(cur, d2buf);
    knn_kernel<HID><<<dim3(16, BATCH), 512, 0, stream>>>(cur, d2buf, idxb);
    rowgemm2_kernel<<<(int)(ROWS / 32), 256, 0, stream>>>(cur, w1c + (size_t)i * 4096,
                                                          ba + i * HID, W1b, hxi, hxjb);
    egstats_kernel<<<1024, 256, 0, stream>>>(idxb, hxi, hxjb, partial);
    bn_reduce_finalize_kernel<<<1, 128, 0, stream>>>(ga + i * HID, bea + i * HID, partial, stats);
    egapply_gemm_kernel<<<1024, 256, 0, stream>>>(idxb, hxi, hxjb, stats,
                                                  wb + (size_t)i * 4096, bb + i * HID, nxt);
    const float* t = cur; cur = nxt; nxt = (float*)t;
  }

  pool_kernel<<<BATCH, 256, 0, stream>>>(cur, pooled);
  head_kernel<<<1, 256, 0, stream>>>(pooled, wf1, bf1, gf, bef, wf2, bf2, (float*)d_out);
}